// Round 1
// baseline (1106.731 us; speedup 1.0000x reference)
//
#include <hip/hip_runtime.h>
#include <math.h>

// ---------------------------------------------------------------------------
// Problem constants (B, Cin, Cout, Rout, N1, N2) = (8, 256, 512, 256, 4096, 1024)
// ---------------------------------------------------------------------------

// ===========================================================================
// Kernel 1: per-batch selection vectors.
//   q1v[o] = sum_c q1_w[o,c] * l1[b,c,0]          (512)
//   wvec[b,c] = sum_o k1_w[o,c] * q1v[o]          (256)
// e1[b,0,m] = sum_c wvec[b,c]*l1[b,c,m]  (softmax is monotone -> skip it)
// ===========================================================================
__global__ void __launch_bounds__(256) sel_qw_kernel(
    const float* __restrict__ l1, const float* __restrict__ q1w,
    const float* __restrict__ k1w, float* __restrict__ wvec) {
  const int b = blockIdx.x;
  const int t = threadIdx.x;
  __shared__ float col[256];
  __shared__ float q1v[512];
  col[t] = l1[(long)b * 256 * 4096 + (long)t * 4096];  // l1[b, t, 0]
  __syncthreads();
  for (int o = t; o < 512; o += 256) {
    float s = 0.f;
    const float* row = q1w + (long)o * 256;
    for (int c = 0; c < 256; ++c) s += row[c] * col[c];
    q1v[o] = s;
  }
  __syncthreads();
  float s = 0.f;
  for (int o = 0; o < 512; ++o) s += k1w[(long)o * 256 + t] * q1v[o];
  wvec[b * 256 + t] = s;
}

// ===========================================================================
// Kernel 2: scores[b,m] = sum_c wvec[b,c] * l1[b,c,m]   (f32 — must be exact-ish)
// ===========================================================================
__global__ void __launch_bounds__(256) sel_scores_kernel(
    const float* __restrict__ l1, const float* __restrict__ wvec,
    float* __restrict__ scores) {
  const int b = blockIdx.y;
  const int m = blockIdx.x * 256 + threadIdx.x;
  __shared__ float w[256];
  w[threadIdx.x] = wvec[b * 256 + threadIdx.x];
  __syncthreads();
  const float* base = l1 + (long)b * 256 * 4096 + m;
  float s = 0.f;
  for (int c = 0; c < 256; ++c) s += w[c] * base[(long)c * 4096];
  scores[b * 4096 + m] = s;
}

// ===========================================================================
// Kernel 3: exact top-1024-of-4096 SET selection per batch (radix select).
// Ties at the cutoff take lowest indices (matches lax.top_k stability).
// Downstream is permutation-invariant, so output order is irrelevant.
// ===========================================================================
__global__ void __launch_bounds__(256) topk_select_kernel(
    const float* __restrict__ scores, int* __restrict__ idx_out) {
  const int b = blockIdx.x;
  const int t = threadIdx.x;
  __shared__ unsigned int keys[4096];
  __shared__ unsigned int hist[256];
  __shared__ unsigned int sc_prefix, sc_krem, total_gt_s;
  __shared__ unsigned int partial_gt[256], partial_eq[256];

  for (int m = t; m < 4096; m += 256) {
    unsigned int u = __float_as_uint(scores[b * 4096 + m]);
    u ^= (u & 0x80000000u) ? 0xFFFFFFFFu : 0x80000000u;  // order-preserving map
    keys[m] = u;
  }
  if (t == 0) { sc_prefix = 0u; sc_krem = 1024u; }
  __syncthreads();

  unsigned int prefmask = 0u;
  for (int shift = 24; shift >= 0; shift -= 8) {
    hist[t] = 0u;
    __syncthreads();
    unsigned int prefix = sc_prefix;
    for (int m = t; m < 4096; m += 256) {
      unsigned int key = keys[m];
      if ((key & prefmask) == prefix) atomicAdd(&hist[(key >> shift) & 255u], 1u);
    }
    __syncthreads();
    if (t == 0) {
      unsigned int krem = sc_krem, acc = 0u;
      int bin = 255;
      for (; bin > 0; --bin) {
        if (acc + hist[bin] >= krem) break;
        acc += hist[bin];
      }
      sc_prefix = prefix | ((unsigned int)bin << shift);
      sc_krem = krem - acc;
    }
    prefmask |= (0xFFu << shift);
    __syncthreads();
  }
  const unsigned int cutoff = sc_prefix;
  const unsigned int need = sc_krem;  // # of ==cutoff elements to take

  // counts over contiguous 16-element chunks (index order => stable ties)
  unsigned int gt = 0u, eq = 0u;
  const int base = t * 16;
  for (int i = 0; i < 16; ++i) {
    unsigned int key = keys[base + i];
    gt += (key > cutoff);
    eq += (key == cutoff);
  }
  partial_gt[t] = gt;
  partial_eq[t] = eq;
  __syncthreads();
  if (t == 0) {
    unsigned int ag = 0u, ae = 0u;
    for (int i = 0; i < 256; ++i) {
      unsigned int g = partial_gt[i], e = partial_eq[i];
      partial_gt[i] = ag; partial_eq[i] = ae;
      ag += g; ae += e;
    }
    total_gt_s = ag;
  }
  __syncthreads();
  unsigned int gpos = partial_gt[t], epos = partial_eq[t];
  const unsigned int tot_gt = total_gt_s;
  for (int i = 0; i < 16; ++i) {
    unsigned int key = keys[base + i];
    if (key > cutoff) {
      idx_out[b * 1024 + (gpos++)] = base + i;
    } else if (key == cutoff) {
      unsigned int r = epos++;
      if (r < need) idx_out[b * 1024 + tot_gt + r] = base + i;
    }
  }
}

// ===========================================================================
// Kernel 4: gather selected columns of l1 (256 rows) and xyz1 (3 rows).
// ===========================================================================
__global__ void __launch_bounds__(256) gather_sel_kernel(
    const float* __restrict__ l1, const float* __restrict__ xyz1,
    const int* __restrict__ idx, float* __restrict__ l1_sel,
    float* __restrict__ p1_sel) {
  const int b = blockIdx.y;
  const int j = blockIdx.x * 256 + threadIdx.x;
  const int ix = idx[b * 1024 + j];
  const float* srcL = l1 + (long)b * 256 * 4096 + ix;
  float* dstL = l1_sel + (long)b * 256 * 1024 + j;
  for (int c = 0; c < 256; ++c) dstL[(long)c * 1024] = srcL[(long)c * 4096];
  const float* srcP = xyz1 + (long)b * 3 * 4096 + ix;
  float* dstP = p1_sel + (long)b * 3 * 1024 + j;
  for (int c = 0; c < 3; ++c) dstP[(long)c * 1024] = srcP[(long)c * 4096];
}

// ===========================================================================
// Kernel 5: generic f32 tiled GEMM   Y[b] = alpha * op(A) @ op(B) + bias + res
//   A logical (O x K):  A_COL=false -> A[o*ldA+k] ; A_COL=true -> A[k*ldA+o]
//   B logical (K x N):  B_TRANS=false -> B[k*ldB+n] ; true -> B[n*ldB+k]
//   Y (O x N) row-major ld=ldY. Tiles 64x64x16, 256 thr, 4x4 microtile.
// ===========================================================================
template <bool A_COL, bool B_TRANS, bool RES>
__global__ void __launch_bounds__(256) gemm_f32(
    const float* __restrict__ A, long strideA, int ldA,
    const float* __restrict__ Bp, long strideB, int ldB,
    float* __restrict__ Y, long strideY, int ldY,
    const float* __restrict__ bias, const float* __restrict__ res,
    long strideR, int K, float alpha) {
  __shared__ __align__(16) float shA[16][68];
  __shared__ __align__(16) float shB[16][68];
  const int tid = threadIdx.x;
  const int tx = tid & 15, ty = tid >> 4;
  const int n0 = blockIdx.x * 64, o0 = blockIdx.y * 64, b = blockIdx.z;
  A += (long)b * strideA;
  Bp += (long)b * strideB;
  Y += (long)b * strideY;
  if (RES) res += (long)b * strideR;

  float acc[4][4] = {};
  for (int k0 = 0; k0 < K; k0 += 16) {
    if (A_COL) {
      const int row = tid >> 4, seg = tid & 15;
      const float4 v = *(const float4*)(A + (long)(k0 + row) * ldA + o0 + seg * 4);
      shA[row][seg * 4 + 0] = v.x; shA[row][seg * 4 + 1] = v.y;
      shA[row][seg * 4 + 2] = v.z; shA[row][seg * 4 + 3] = v.w;
    } else {
      const int oo = tid >> 2, kseg = tid & 3;
      const float4 v = *(const float4*)(A + (long)(o0 + oo) * ldA + k0 + kseg * 4);
      shA[kseg * 4 + 0][oo] = v.x; shA[kseg * 4 + 1][oo] = v.y;
      shA[kseg * 4 + 2][oo] = v.z; shA[kseg * 4 + 3][oo] = v.w;
    }
    if (!B_TRANS) {
      const int row = tid >> 4, seg = tid & 15;
      const float4 v = *(const float4*)(Bp + (long)(k0 + row) * ldB + n0 + seg * 4);
      shB[row][seg * 4 + 0] = v.x; shB[row][seg * 4 + 1] = v.y;
      shB[row][seg * 4 + 2] = v.z; shB[row][seg * 4 + 3] = v.w;
    } else {
      const int nn = tid >> 2, kseg = tid & 3;
      const float4 v = *(const float4*)(Bp + (long)(n0 + nn) * ldB + k0 + kseg * 4);
      shB[kseg * 4 + 0][nn] = v.x; shB[kseg * 4 + 1][nn] = v.y;
      shB[kseg * 4 + 2][nn] = v.z; shB[kseg * 4 + 3][nn] = v.w;
    }
    __syncthreads();
#pragma unroll
    for (int kk = 0; kk < 16; ++kk) {
      const float4 av = *(const float4*)&shA[kk][ty * 4];
      const float4 bv = *(const float4*)&shB[kk][tx * 4];
      const float a[4] = {av.x, av.y, av.z, av.w};
      const float bb[4] = {bv.x, bv.y, bv.z, bv.w};
#pragma unroll
      for (int i = 0; i < 4; ++i)
#pragma unroll
        for (int j = 0; j < 4; ++j) acc[i][j] += a[i] * bb[j];
    }
    __syncthreads();
  }
#pragma unroll
  for (int i = 0; i < 4; ++i) {
    const int o = o0 + ty * 4 + i;
    const float bi = bias ? bias[o] : 0.f;
    float4 out;
    float* yp = Y + (long)o * ldY + n0 + tx * 4;
    out.x = acc[i][0] * alpha + bi;
    out.y = acc[i][1] * alpha + bi;
    out.z = acc[i][2] * alpha + bi;
    out.w = acc[i][3] * alpha + bi;
    if (RES) {
      const float4 rv = *(const float4*)(res + (long)o * ldY + n0 + tx * 4);
      out.x += rv.x; out.y += rv.y; out.z += rv.z; out.w += rv.w;
    }
    *(float4*)yp = out;
  }
}

// ===========================================================================
// Kernel 6: per-column LayerNorm over the channel (row) axis + activation.
//   y = act( (x - mean) * rsqrt(var + 1e-5) * g[r] + be[r] )
//   act(x) = x > 0 ? x : slope * x    (slope=0 -> relu, 0.01 -> leaky)
// In-place safe. Block (64 cols x 4), grid (N/64, B).
// ===========================================================================
__global__ void __launch_bounds__(256) col_ln_kernel(
    const float* __restrict__ T, float* __restrict__ Yout,
    const float* __restrict__ g, const float* __restrict__ be, int O,
    float slope, long batch_stride) {
  const int b = blockIdx.y;
  const int n = blockIdx.x * 64 + threadIdx.x;
  const int ty = threadIdx.y;
  const float* Tb = T + (long)b * batch_stride + n;
  float sum = 0.f, sumsq = 0.f;
  for (int r = ty; r < O; r += 4) {
    const float x = Tb[(long)r * 1024];
    sum += x;
    sumsq += x * x;
  }
  __shared__ float s1[4][64], s2[4][64];
  s1[ty][threadIdx.x] = sum;
  s2[ty][threadIdx.x] = sumsq;
  __syncthreads();
  float ts = 0.f, tq = 0.f;
  for (int i = 0; i < 4; ++i) {
    ts += s1[i][threadIdx.x];
    tq += s2[i][threadIdx.x];
  }
  const float invO = 1.f / (float)O;
  const float mean = ts * invO;
  const float var = tq * invO - mean * mean;
  const float rstd = rsqrtf(var + 1e-5f);
  float* Yb = Yout + (long)b * batch_stride + n;
  for (int r = ty; r < O; r += 4) {
    const float x = Tb[(long)r * 1024];
    float y = (x - mean) * rstd * g[r] + be[r];
    y = (y > 0.f) ? y : slope * y;
    Yb[(long)r * 1024] = y;
  }
}

// ===========================================================================
// Kernel 7: Y[b,o,n] = X[b,o,n] + posw[o,0]*P[b,0,n] + posw[o,1]*P[b,1,n]
//                                + posw[o,2]*P[b,2,n]
// ===========================================================================
__global__ void __launch_bounds__(256) pos_add_kernel(
    const float* __restrict__ X, const float* __restrict__ P,
    const float* __restrict__ posw, float* __restrict__ Y, int O) {
  const int b = blockIdx.y;
  const int n = blockIdx.x * 256 + threadIdx.x;
  const float p0 = P[(long)b * 3 * 1024 + n];
  const float p1 = P[(long)b * 3 * 1024 + 1024 + n];
  const float p2 = P[(long)b * 3 * 1024 + 2048 + n];
  const float* Xb = X + (long)b * O * 1024 + n;
  float* Yb = Y + (long)b * O * 1024 + n;
  for (int o = 0; o < O; ++o) {
    Yb[(long)o * 1024] =
        Xb[(long)o * 1024] + posw[o * 3] * p0 + posw[o * 3 + 1] * p1 + posw[o * 3 + 2] * p2;
  }
}

// ===========================================================================
// Kernel 8: in-place softmax over rows of E (rows of length 1024).
// ===========================================================================
__global__ void __launch_bounds__(256) softmax_rows_kernel(float* __restrict__ E) {
  const long row = blockIdx.x;
  float* p = E + row * 1024;
  const int t = threadIdx.x;
  float v[4];
  float m = -INFINITY;
#pragma unroll
  for (int i = 0; i < 4; ++i) {
    v[i] = p[t + i * 256];
    m = fmaxf(m, v[i]);
  }
  __shared__ float sm[256];
  sm[t] = m;
  __syncthreads();
  for (int s = 128; s > 0; s >>= 1) {
    if (t < s) sm[t] = fmaxf(sm[t], sm[t + s]);
    __syncthreads();
  }
  m = sm[0];
  __syncthreads();
  float sum = 0.f;
#pragma unroll
  for (int i = 0; i < 4; ++i) {
    v[i] = expf(v[i] - m);
    sum += v[i];
  }
  sm[t] = sum;
  __syncthreads();
  for (int s = 128; s > 0; s >>= 1) {
    if (t < s) sm[t] += sm[t + s];
    __syncthreads();
  }
  const float inv = 1.f / sm[0];
#pragma unroll
  for (int i = 0; i < 4; ++i) p[t + i * 256] = v[i] * inv;
}

// ===========================================================================
// Launch
// ===========================================================================
extern "C" void kernel_launch(void* const* d_in, const int* in_sizes, int n_in,
                              void* d_out, int out_size, void* d_ws,
                              size_t ws_size, hipStream_t stream) {
  const float* l1 = (const float*)d_in[0];
  const float* xyz1 = (const float*)d_in[1];
  const float* l2 = (const float*)d_in[2];
  const float* xyz2 = (const float*)d_in[3];
  const float* q1w = (const float*)d_in[4];
  const float* k1w = (const float*)d_in[5];
  const float* mlp_w1 = (const float*)d_in[6];
  const float* mlp_b1 = (const float*)d_in[7];
  const float* mlp_g1 = (const float*)d_in[8];
  const float* mlp_be1 = (const float*)d_in[9];
  const float* mlp_w2 = (const float*)d_in[10];
  const float* mlp_b2 = (const float*)d_in[11];
  const float* qw = (const float*)d_in[12];
  const float* kw = (const float*)d_in[13];
  const float* vw = (const float*)d_in[14];
  const float* posw = (const float*)d_in[15];
  const float* norm_g = (const float*)d_in[16];
  const float* norm_b = (const float*)d_in[17];
  const float* m1_w1 = (const float*)d_in[18];
  const float* m1_b1 = (const float*)d_in[19];
  const float* m1_g = (const float*)d_in[20];
  const float* m1_be = (const float*)d_in[21];
  const float* m1_w2 = (const float*)d_in[22];
  const float* m1_b2 = (const float*)d_in[23];

  char* ws = (char*)d_ws;
  // Region layout with liveness-based reuse (peak 112 MB):
  //   [0, 32MB): early buffers (l1_sel/h1/p1_sel/scores/wvec/idx), later e/att
  float* l1_sel = (float*)(ws + 0);            // 8 MB, dead before e
  float* h1     = (float*)(ws + 8388608);      // 8 MB, dead before e
  float* p1_sel = (float*)(ws + 16777216);     // 96 KB, dead before e
  float* scores = (float*)(ws + 16875520);     // 128 KB
  float* wvec   = (float*)(ws + 17006592);     // 8 KB
  int*   idxb   = (int*)(ws + 17014784);       // 32 KB
  float* e      = (float*)(ws + 0);            // 32 MB (att in place)
  float* qbuf   = (float*)(ws + 33554432);     // 16 MB: q, later O (attn out)
  float* kbuf   = (float*)(ws + 50331648);     // 16 MB: k, later g2
  float* vbuf   = (float*)(ws + 67108864);     // 16 MB
  float* x2     = (float*)(ws + 83886080);     // 16 MB
  float* tbuf   = (float*)(ws + 100663296);    // 16 MB: qin then kin
  float* outp   = (float*)d_out;

  const float inv_scale = 1.0f / sqrtf(512.0f);
  const long S256 = 256L * 1024, S512 = 512L * 1024, S1024 = 1024L * 1024;

  // --- selection path (exact f32) ---
  sel_qw_kernel<<<8, 256, 0, stream>>>(l1, q1w, k1w, wvec);
  sel_scores_kernel<<<dim3(16, 8), 256, 0, stream>>>(l1, wvec, scores);
  topk_select_kernel<<<8, 256, 0, stream>>>(scores, idxb);
  gather_sel_kernel<<<dim3(4, 8), 256, 0, stream>>>(l1, xyz1, idxb, l1_sel, p1_sel);

  // --- point MLP: h1 = relu(LN(mlp_w1 @ l1_sel + b1)); x2 = mlp_w2 @ h1 + b2
  gemm_f32<false, false, false><<<dim3(16, 4, 8), 256, 0, stream>>>(
      mlp_w1, 0, 256, l1_sel, S256, 1024, h1, S256, 1024, mlp_b1, nullptr, 0, 256, 1.0f);
  col_ln_kernel<<<dim3(16, 8), dim3(64, 4), 0, stream>>>(h1, h1, mlp_g1, mlp_be1, 256, 0.0f, S256);
  gemm_f32<false, false, false><<<dim3(16, 8, 8), 256, 0, stream>>>(
      mlp_w2, 0, 256, h1, S256, 1024, x2, S512, 1024, mlp_b2, nullptr, 0, 256, 1.0f);

  // --- q/k/v ---
  pos_add_kernel<<<dim3(4, 8), 256, 0, stream>>>(l2, xyz2, posw, tbuf, 512);
  gemm_f32<false, false, false><<<dim3(16, 8, 8), 256, 0, stream>>>(
      qw, 0, 512, tbuf, S512, 1024, qbuf, S512, 1024, nullptr, nullptr, 0, 512, 1.0f);
  pos_add_kernel<<<dim3(4, 8), 256, 0, stream>>>(x2, p1_sel, posw, tbuf, 512);
  gemm_f32<false, false, false><<<dim3(16, 8, 8), 256, 0, stream>>>(
      kw, 0, 512, tbuf, S512, 1024, kbuf, S512, 1024, nullptr, nullptr, 0, 512, 1.0f);
  gemm_f32<false, false, false><<<dim3(16, 8, 8), 256, 0, stream>>>(
      vw, 0, 512, x2, S512, 1024, vbuf, S512, 1024, nullptr, nullptr, 0, 512, 1.0f);

  // --- attention: e = q^T k / scale ; softmax ; O = v @ att^T + l2 ---
  gemm_f32<true, false, false><<<dim3(16, 16, 8), 256, 0, stream>>>(
      qbuf, S512, 1024, kbuf, S512, 1024, e, S1024, 1024, nullptr, nullptr, 0, 512, inv_scale);
  softmax_rows_kernel<<<8192, 256, 0, stream>>>(e);
  gemm_f32<false, true, true><<<dim3(16, 8, 8), 256, 0, stream>>>(
      vbuf, S512, 1024, e, S1024, 1024, qbuf, S512, 1024, nullptr, l2, S512, 1024, 1.0f);

  // --- head: leaky(LN) -> m1_w1 -> relu(LN) -> m1_w2 ---
  col_ln_kernel<<<dim3(16, 8), dim3(64, 4), 0, stream>>>(qbuf, qbuf, norm_g, norm_b, 512, 0.01f, S512);
  gemm_f32<false, false, false><<<dim3(16, 8, 8), 256, 0, stream>>>(
      m1_w1, 0, 512, qbuf, S512, 1024, kbuf, S512, 1024, m1_b1, nullptr, 0, 512, 1.0f);
  col_ln_kernel<<<dim3(16, 8), dim3(64, 4), 0, stream>>>(kbuf, kbuf, m1_g, m1_be, 512, 0.0f, S512);
  gemm_f32<false, false, false><<<dim3(16, 4, 8), 256, 0, stream>>>(
      m1_w2, 0, 512, kbuf, S512, 1024, outp, S256, 1024, m1_b2, nullptr, 0, 512, 1.0f);
}

// Round 2
// 460.171 us; speedup vs baseline: 2.4050x; 2.4050x over previous
//
#include <hip/hip_runtime.h>
#include <math.h>

// ---------------------------------------------------------------------------
// (B, Cin, Cout, Rout, N1, N2) = (8, 256, 512, 256, 4096, 1024)
// All activations token-major: X[b][n][c] (c contiguous) except v [c][m].
// ---------------------------------------------------------------------------

typedef __attribute__((ext_vector_type(8))) short short8x;
typedef __attribute__((ext_vector_type(4))) float f32x4;

__device__ __forceinline__ unsigned short f2b(float f) {
  unsigned int u = __float_as_uint(f);
  unsigned int r = u + 0x7FFFu + ((u >> 16) & 1u);
  return (unsigned short)(r >> 16);
}
__device__ __forceinline__ float b2f(unsigned short h) {
  return __uint_as_float(((unsigned int)h) << 16);
}

__device__ __forceinline__ void cp16(const unsigned short* g, unsigned short* l) {
  __builtin_amdgcn_global_load_lds(
      (const __attribute__((address_space(1))) void*)g,
      (__attribute__((address_space(3))) void*)l, 16, 0, 0);
}

// ===========================================================================
// Selection path (exact f32 — top-k set identity requires it)
// ===========================================================================
__global__ void __launch_bounds__(256) sel_qw_kernel(
    const float* __restrict__ l1, const float* __restrict__ q1w,
    const float* __restrict__ k1w, float* __restrict__ wvec) {
  const int b = blockIdx.x;
  const int t = threadIdx.x;
  __shared__ float col[256];
  __shared__ float q1v[512];
  col[t] = l1[(long)b * 256 * 4096 + (long)t * 4096];
  __syncthreads();
  for (int o = t; o < 512; o += 256) {
    float s = 0.f;
    const float* row = q1w + (long)o * 256;
    for (int c = 0; c < 256; ++c) s += row[c] * col[c];
    q1v[o] = s;
  }
  __syncthreads();
  float s = 0.f;
  for (int o = 0; o < 512; ++o) s += k1w[(long)o * 256 + t] * q1v[o];
  wvec[b * 256 + t] = s;
}

__global__ void __launch_bounds__(256) sel_scores_kernel(
    const float* __restrict__ l1, const float* __restrict__ wvec,
    float* __restrict__ scores) {
  const int b = blockIdx.y;
  const int m = blockIdx.x * 256 + threadIdx.x;
  __shared__ float w[256];
  w[threadIdx.x] = wvec[b * 256 + threadIdx.x];
  __syncthreads();
  const float* base = l1 + (long)b * 256 * 4096 + m;
  float s = 0.f;
  for (int c = 0; c < 256; ++c) s += w[c] * base[(long)c * 4096];
  scores[b * 4096 + m] = s;
}

__global__ void __launch_bounds__(256) topk_select_kernel(
    const float* __restrict__ scores, int* __restrict__ idx_out) {
  const int b = blockIdx.x;
  const int t = threadIdx.x;
  __shared__ unsigned int keys[4096];
  __shared__ unsigned int hist[256];
  __shared__ unsigned int sc_prefix, sc_krem, total_gt_s;
  __shared__ unsigned int partial_gt[256], partial_eq[256];

  for (int m = t; m < 4096; m += 256) {
    unsigned int u = __float_as_uint(scores[b * 4096 + m]);
    u ^= (u & 0x80000000u) ? 0xFFFFFFFFu : 0x80000000u;
    keys[m] = u;
  }
  if (t == 0) { sc_prefix = 0u; sc_krem = 1024u; }
  __syncthreads();

  unsigned int prefmask = 0u;
  for (int shift = 24; shift >= 0; shift -= 8) {
    hist[t] = 0u;
    __syncthreads();
    unsigned int prefix = sc_prefix;
    for (int m = t; m < 4096; m += 256) {
      unsigned int key = keys[m];
      if ((key & prefmask) == prefix) atomicAdd(&hist[(key >> shift) & 255u], 1u);
    }
    __syncthreads();
    if (t == 0) {
      unsigned int krem = sc_krem, acc = 0u;
      int bin = 255;
      for (; bin > 0; --bin) {
        if (acc + hist[bin] >= krem) break;
        acc += hist[bin];
      }
      sc_prefix = prefix | ((unsigned int)bin << shift);
      sc_krem = krem - acc;
    }
    prefmask |= (0xFFu << shift);
    __syncthreads();
  }
  const unsigned int cutoff = sc_prefix;
  const unsigned int need = sc_krem;

  unsigned int gt = 0u, eq = 0u;
  const int base = t * 16;
  for (int i = 0; i < 16; ++i) {
    unsigned int key = keys[base + i];
    gt += (key > cutoff);
    eq += (key == cutoff);
  }
  partial_gt[t] = gt;
  partial_eq[t] = eq;
  __syncthreads();
  if (t == 0) {
    unsigned int ag = 0u, ae = 0u;
    for (int i = 0; i < 256; ++i) {
      unsigned int g = partial_gt[i], e = partial_eq[i];
      partial_gt[i] = ag; partial_eq[i] = ae;
      ag += g; ae += e;
    }
    total_gt_s = ag;
  }
  __syncthreads();
  unsigned int gpos = partial_gt[t], epos = partial_eq[t];
  const unsigned int tot_gt = total_gt_s;
  for (int i = 0; i < 16; ++i) {
    unsigned int key = keys[base + i];
    if (key > cutoff) {
      idx_out[b * 1024 + (gpos++)] = base + i;
    } else if (key == cutoff) {
      unsigned int r = epos++;
      if (r < need) idx_out[b * 1024 + tot_gt + r] = base + i;
    }
  }
}

// ===========================================================================
// Gather: l1selT[b][j][c] bf16 (token-major), p1selT[b][j][d] f32
// ===========================================================================
__global__ void __launch_bounds__(256) gather_sel_kernel(
    const float* __restrict__ l1, const float* __restrict__ xyz1,
    const int* __restrict__ idx, unsigned short* __restrict__ l1selT,
    float* __restrict__ p1selT) {
  const int b = blockIdx.y;
  const int j = blockIdx.x * 256 + threadIdx.x;
  const int ix = idx[b * 1024 + j];
  const float* srcL = l1 + (long)b * 256 * 4096 + ix;
  unsigned short* dstL = l1selT + ((long)b * 1024 + j) * 256;
  for (int c = 0; c < 256; c += 4) {
    ushort4 o;
    o.x = f2b(srcL[(long)(c + 0) * 4096]);
    o.y = f2b(srcL[(long)(c + 1) * 4096]);
    o.z = f2b(srcL[(long)(c + 2) * 4096]);
    o.w = f2b(srcL[(long)(c + 3) * 4096]);
    *(ushort4*)&dstL[c] = o;
  }
  float* dstP = p1selT + ((long)b * 1024 + j) * 3;
  for (int d = 0; d < 3; ++d) dstP[d] = xyz1[((long)b * 3 + d) * 4096 + ix];
}

// ===========================================================================
// Weight convert f32 -> bf16 (7 weights, one launch)
// ===========================================================================
__global__ void __launch_bounds__(256) conv_weights_kernel(
    const float* w0, const float* w1, const float* w2, const float* w3,
    const float* w4, const float* w5, const float* w6,
    unsigned short* d0, unsigned short* d1, unsigned short* d2,
    unsigned short* d3, unsigned short* d4, unsigned short* d5,
    unsigned short* d6) {
  const float* src;
  unsigned short* dst;
  int n;
  switch (blockIdx.y) {
    case 0: src = w0; dst = d0; n = 65536; break;
    case 1: src = w1; dst = d1; n = 131072; break;
    case 2: src = w2; dst = d2; n = 262144; break;
    case 3: src = w3; dst = d3; n = 262144; break;
    case 4: src = w4; dst = d4; n = 262144; break;
    case 5: src = w5; dst = d5; n = 262144; break;
    default: src = w6; dst = d6; n = 131072; break;
  }
  const int i = (blockIdx.x * 256 + threadIdx.x) * 4;
  if (i < n) {
    const float4 v = *(const float4*)(src + i);
    ushort4 o;
    o.x = f2b(v.x); o.y = f2b(v.y); o.z = f2b(v.z); o.w = f2b(v.w);
    *(ushort4*)(dst + i) = o;
  }
}

// ===========================================================================
// Transpose l2 -> token-major + pos_q:  qinT[n][c] bf16 = l2[c][n] + posw[c]·xyz2[:,n]
//                                       l2T[n][c] f32  = l2[c][n]   (residual)
// ===========================================================================
__global__ void __launch_bounds__(256) transpose_posq_kernel(
    const float* __restrict__ l2, const float* __restrict__ xyz2,
    const float* __restrict__ posw, unsigned short* __restrict__ qinT,
    float* __restrict__ l2T) {
  const int b = blockIdx.z;
  const int n0 = blockIdx.x * 64, c0 = blockIdx.y * 64;
  const int tx = threadIdx.x, ty = threadIdx.y;
  __shared__ float tile[64][65];
  __shared__ float sx[3][64];
  const float* l2b = l2 + (long)b * 512 * 1024;
  for (int r = 0; r < 16; ++r) {
    const int c = ty * 16 + r;
    tile[c][tx] = l2b[(long)(c0 + c) * 1024 + n0 + tx];
  }
  if (ty < 3) sx[ty][tx] = xyz2[((long)b * 3 + ty) * 1024 + n0 + tx];
  __syncthreads();
  const int c = c0 + tx;
  const float p0 = posw[c * 3], p1 = posw[c * 3 + 1], p2 = posw[c * 3 + 2];
  for (int r = 0; r < 16; ++r) {
    const int nl = ty * 16 + r;
    const float val = tile[tx][nl];
    const long o = ((long)b * 1024 + n0 + nl) * 512 + c;
    l2T[o] = val;
    qinT[o] = f2b(val + p0 * sx[0][nl] + p1 * sx[1][nl] + p2 * sx[2][nl]);
  }
}

// ===========================================================================
// kinT[n][c] bf16 = x2T[n][c] + posw[c]·p1selT[n][:]
// ===========================================================================
__global__ void __launch_bounds__(128) kin_kernel(
    const unsigned short* __restrict__ x2T, const float* __restrict__ p1selT,
    const float* __restrict__ posw, unsigned short* __restrict__ kinT) {
  const long row = blockIdx.x;  // b*1024+n
  const int t = threadIdx.x;
  const float q0 = p1selT[row * 3], q1 = p1selT[row * 3 + 1], q2 = p1selT[row * 3 + 2];
  const int c = t * 4;
  const ushort4 xv = *(const ushort4*)&x2T[row * 512 + c];
  ushort4 o;
  o.x = f2b(b2f(xv.x) + posw[(c + 0) * 3] * q0 + posw[(c + 0) * 3 + 1] * q1 + posw[(c + 0) * 3 + 2] * q2);
  o.y = f2b(b2f(xv.y) + posw[(c + 1) * 3] * q0 + posw[(c + 1) * 3 + 1] * q1 + posw[(c + 1) * 3 + 2] * q2);
  o.z = f2b(b2f(xv.z) + posw[(c + 2) * 3] * q0 + posw[(c + 2) * 3 + 1] * q1 + posw[(c + 2) * 3 + 2] * q2);
  o.w = f2b(b2f(xv.w) + posw[(c + 3) * 3] * q0 + posw[(c + 3) * 3 + 1] * q1 + posw[(c + 3) * 3 + 2] * q2);
  *(ushort4*)&kinT[row * 512 + c] = o;
}

// ===========================================================================
// MFMA bf16 GEMM: D[M][N] = alpha * A[M][K] · Bt[N][K]^T (+bias)(+res)
// 128x128 tile, 4 waves (2x2 of 64x64), BK=32, global_load_lds width=16,
// XOR-swizzled LDS (via gptr permutation) -> 2-way max bank conflicts.
// ===========================================================================
template <bool BIAS_COL, bool BIAS_ROW, bool RES, bool OUT_BF16>
__global__ void __launch_bounds__(256) gemm_bf16(
    const unsigned short* __restrict__ A, long sA, int ldA,
    const unsigned short* __restrict__ Bt, long sB, int ldB,
    void* __restrict__ Yv, long sY, int ldY,
    const float* __restrict__ bias, const float* __restrict__ res, long sR,
    int K, float alpha) {
  __shared__ __align__(16) unsigned short ldsA[128 * 32];
  __shared__ __align__(16) unsigned short ldsB[128 * 32];
  const int tid = threadIdx.x;
  const int lane = tid & 63;
  const int wv = tid >> 6;
  const int wm = wv >> 1, wn = wv & 1;
  const int n0 = blockIdx.x * 128, m0 = blockIdx.y * 128, b = blockIdx.z;
  A += (long)b * sA;
  Bt += (long)b * sB;
  const int lane15 = lane & 15, q = lane >> 4;

  // staging addresses (per wave: 2 ops of 16 rows x 32k for A and for B)
  const int srow0 = wv * 32 + (lane >> 2);       // t=0 row (tile-local)
  const int srow1 = srow0 + 16;                  // t=1 row
  const int ks0 = ((lane & 3) ^ ((srow0 >> 1) & 3)) << 3;
  const int ks1 = ((lane & 3) ^ ((srow1 >> 1) & 3)) << 3;
  unsigned short* lA0 = ldsA + (wv * 32) * 32;
  unsigned short* lA1 = ldsA + (wv * 32 + 16) * 32;
  unsigned short* lB0 = ldsB + (wv * 32) * 32;
  unsigned short* lB1 = ldsB + (wv * 32 + 16) * 32;

  f32x4 acc[4][4] = {};
  for (int k0 = 0; k0 < K; k0 += 32) {
    __syncthreads();
    cp16(A + (long)(m0 + srow0) * ldA + k0 + ks0, lA0);
    cp16(A + (long)(m0 + srow1) * ldA + k0 + ks1, lA1);
    cp16(Bt + (long)(n0 + srow0) * ldB + k0 + ks0, lB0);
    cp16(Bt + (long)(n0 + srow1) * ldB + k0 + ks1, lB1);
    __syncthreads();
    short8x af[4], bfr[4];
#pragma unroll
    for (int i = 0; i < 4; ++i) {
      const int m = wm * 64 + i * 16 + lane15;
      af[i] = *(const short8x*)&ldsA[m * 32 + ((q ^ ((m >> 1) & 3)) << 3)];
      const int n = wn * 64 + i * 16 + lane15;
      bfr[i] = *(const short8x*)&ldsB[n * 32 + ((q ^ ((n >> 1) & 3)) << 3)];
    }
#pragma unroll
    for (int i = 0; i < 4; ++i)
#pragma unroll
      for (int j = 0; j < 4; ++j)
        acc[i][j] = __builtin_amdgcn_mfma_f32_16x16x32_bf16(af[i], bfr[j], acc[i][j], 0, 0, 0);
  }

  // epilogue: C/D layout col=lane&15, row=(lane>>4)*4+reg [m89]
  float* Yf = (float*)Yv + (OUT_BF16 ? 0 : (long)b * sY);
  unsigned short* Yh = (unsigned short*)Yv + (OUT_BF16 ? (long)b * sY : 0);
  if (RES) res += (long)b * sR;
#pragma unroll
  for (int i = 0; i < 4; ++i) {
#pragma unroll
    for (int j = 0; j < 4; ++j) {
      const int n_g = n0 + wn * 64 + j * 16 + lane15;
      const float bc = BIAS_COL ? bias[n_g] : 0.f;
#pragma unroll
      for (int r = 0; r < 4; ++r) {
        const int m_g = m0 + wm * 64 + i * 16 + q * 4 + r;
        float y = acc[i][j][r] * alpha + bc;
        if (BIAS_ROW) y += bias[m_g];
        const long off = (long)m_g * ldY + n_g;
        if (RES) y += res[off];
        if (OUT_BF16) Yh[off] = f2b(y);
        else Yf[off] = y;
      }
    }
  }
}

// ===========================================================================
// Row LayerNorm (+act) over contiguous rows, f32 in -> bf16 out.
// Block 256 = 4 waves, one wave per row.
// ===========================================================================
template <int C>
__global__ void __launch_bounds__(256) row_ln_kernel(
    const float* __restrict__ X, unsigned short* __restrict__ Y,
    const float* __restrict__ g, const float* __restrict__ be, float slope) {
  const int lane = threadIdx.x & 63;
  const long row = (long)blockIdx.x * 4 + (threadIdx.x >> 6);
  const float* xr = X + row * C;
  constexpr int V = C / 256;  // float4s per lane (1 or 2)
  float4 v[V];
  float s = 0.f, sq = 0.f;
#pragma unroll
  for (int u = 0; u < V; ++u) {
    v[u] = ((const float4*)xr)[lane * V + u];
    s += v[u].x + v[u].y + v[u].z + v[u].w;
    sq += v[u].x * v[u].x + v[u].y * v[u].y + v[u].z * v[u].z + v[u].w * v[u].w;
  }
#pragma unroll
  for (int off = 32; off > 0; off >>= 1) {
    s += __shfl_xor(s, off);
    sq += __shfl_xor(sq, off);
  }
  const float mean = s / (float)C;
  const float var = sq / (float)C - mean * mean;
  const float rstd = rsqrtf(var + 1e-5f);
  unsigned short* yr = Y + row * C;
#pragma unroll
  for (int u = 0; u < V; ++u) {
    const int c = (lane * V + u) * 4;
    const float4 gv = ((const float4*)g)[lane * V + u];
    const float4 bv = ((const float4*)be)[lane * V + u];
    float y0 = (v[u].x - mean) * rstd * gv.x + bv.x;
    float y1 = (v[u].y - mean) * rstd * gv.y + bv.y;
    float y2 = (v[u].z - mean) * rstd * gv.z + bv.z;
    float y3 = (v[u].w - mean) * rstd * gv.w + bv.w;
    y0 = y0 > 0.f ? y0 : slope * y0;
    y1 = y1 > 0.f ? y1 : slope * y1;
    y2 = y2 > 0.f ? y2 : slope * y2;
    y3 = y3 > 0.f ? y3 : slope * y3;
    ushort4 o;
    o.x = f2b(y0); o.y = f2b(y1); o.z = f2b(y2); o.w = f2b(y3);
    *(ushort4*)&yr[c] = o;
  }
}

// ===========================================================================
// Softmax over rows of 1024, f32 in -> bf16 out
// ===========================================================================
__global__ void __launch_bounds__(256) softmax_bf16_kernel(
    const float* __restrict__ E, unsigned short* __restrict__ att) {
  const long row = blockIdx.x;
  const int t = threadIdx.x;
  float4 v = ((const float4*)(E + row * 1024))[t];
  float m = fmaxf(fmaxf(v.x, v.y), fmaxf(v.z, v.w));
  __shared__ float sm[256];
  sm[t] = m;
  __syncthreads();
  for (int s = 128; s > 0; s >>= 1) {
    if (t < s) sm[t] = fmaxf(sm[t], sm[t + s]);
    __syncthreads();
  }
  m = sm[0];
  __syncthreads();
  v.x = expf(v.x - m); v.y = expf(v.y - m);
  v.z = expf(v.z - m); v.w = expf(v.w - m);
  sm[t] = v.x + v.y + v.z + v.w;
  __syncthreads();
  for (int s = 128; s > 0; s >>= 1) {
    if (t < s) sm[t] += sm[t + s];
    __syncthreads();
  }
  const float inv = 1.f / sm[0];
  ushort4 o;
  o.x = f2b(v.x * inv); o.y = f2b(v.y * inv);
  o.z = f2b(v.z * inv); o.w = f2b(v.w * inv);
  ((ushort4*)(att + row * 1024))[t] = o;
}

// ===========================================================================
// Launch
// ===========================================================================
extern "C" void kernel_launch(void* const* d_in, const int* in_sizes, int n_in,
                              void* d_out, int out_size, void* d_ws,
                              size_t ws_size, hipStream_t stream) {
  const float* l1 = (const float*)d_in[0];
  const float* xyz1 = (const float*)d_in[1];
  const float* l2 = (const float*)d_in[2];
  const float* xyz2 = (const float*)d_in[3];
  const float* q1w = (const float*)d_in[4];
  const float* k1w = (const float*)d_in[5];
  const float* mlp_w1 = (const float*)d_in[6];
  const float* mlp_b1 = (const float*)d_in[7];
  const float* mlp_g1 = (const float*)d_in[8];
  const float* mlp_be1 = (const float*)d_in[9];
  const float* mlp_w2 = (const float*)d_in[10];
  const float* mlp_b2 = (const float*)d_in[11];
  const float* qw = (const float*)d_in[12];
  const float* kw = (const float*)d_in[13];
  const float* vw = (const float*)d_in[14];
  const float* posw = (const float*)d_in[15];
  const float* norm_g = (const float*)d_in[16];
  const float* norm_b = (const float*)d_in[17];
  const float* m1_w1 = (const float*)d_in[18];
  const float* m1_b1 = (const float*)d_in[19];
  const float* m1_g = (const float*)d_in[20];
  const float* m1_be = (const float*)d_in[21];
  const float* m1_w2 = (const float*)d_in[22];
  const float* m1_b2 = (const float*)d_in[23];

  char* ws = (char*)d_ws;
  const long MiB = 1048576;
  // small region [0, 4 MiB)
  unsigned short* wb_mlp_w1 = (unsigned short*)(ws + 0);
  unsigned short* wb_mlp_w2 = (unsigned short*)(ws + 131072);
  unsigned short* wb_qw = (unsigned short*)(ws + 393216);
  unsigned short* wb_kw = (unsigned short*)(ws + 917504);
  unsigned short* wb_vw = (unsigned short*)(ws + 1441792);
  unsigned short* wb_m1w1 = (unsigned short*)(ws + 1966080);
  unsigned short* wb_m1w2 = (unsigned short*)(ws + 2490368);
  float* scores = (float*)(ws + 2752512);
  float* wvec = (float*)(ws + 2883584);
  int* idxb = (int*)(ws + 2891776);
  float* p1selT = (float*)(ws + 2924544);
  // big buffers
  float* e = (float*)(ws + 4 * MiB);                 // [4,36) f32
  unsigned short* l1selT = (unsigned short*)(ws + 4 * MiB);   // dead before e
  float* h1raw = (float*)(ws + 8 * MiB);                      // dead before e
  unsigned short* h1T = (unsigned short*)(ws + 16 * MiB);     // dead before e
  unsigned short* qinT = (unsigned short*)(ws + 20 * MiB);    // dead before e
  unsigned short* kinT = (unsigned short*)(ws + 28 * MiB);    // dead before e
  float* l2T = (float*)(ws + 36 * MiB);              // [36,52)
  unsigned short* x2T = (unsigned short*)(ws + 52 * MiB);     // [52,60)
  unsigned short* g2T = (unsigned short*)(ws + 52 * MiB);     // reuse after x2T dead
  unsigned short* qT = (unsigned short*)(ws + 60 * MiB);      // [60,68)
  unsigned short* kT = (unsigned short*)(ws + 68 * MiB);      // [68,76)
  float* oraw = (float*)(ws + 60 * MiB);             // [60,76) reuse qT/kT
  unsigned short* vbf = (unsigned short*)(ws + 76 * MiB);     // [76,84)
  unsigned short* att = (unsigned short*)(ws + 84 * MiB);     // [84,100)
  float* g1raw = (float*)(ws + 84 * MiB);            // reuse after att dead
  unsigned short* o1T = (unsigned short*)(ws + 100 * MiB);    // [100,108)
  float* outp = (float*)d_out;

  const float inv_scale = 1.0f / sqrtf(512.0f);
  const long T256 = 1024L * 256, T512 = 1024L * 512, T1024 = 1024L * 1024;

  // --- selection (f32 exact) + weight conversion ---
  conv_weights_kernel<<<dim3(256, 7), 256, 0, stream>>>(
      mlp_w1, mlp_w2, qw, kw, vw, m1_w1, m1_w2,
      wb_mlp_w1, wb_mlp_w2, wb_qw, wb_kw, wb_vw, wb_m1w1, wb_m1w2);
  sel_qw_kernel<<<8, 256, 0, stream>>>(l1, q1w, k1w, wvec);
  sel_scores_kernel<<<dim3(16, 8), 256, 0, stream>>>(l1, wvec, scores);
  topk_select_kernel<<<8, 256, 0, stream>>>(scores, idxb);
  gather_sel_kernel<<<dim3(4, 8), 256, 0, stream>>>(l1, xyz1, idxb, l1selT, p1selT);

  // --- point MLP ---
  // G1: h1raw[n][c'] = l1selT · mlp_w1^T + b1   (M=1024,N=256,K=256)
  gemm_bf16<true, false, false, false><<<dim3(2, 8, 8), 256, 0, stream>>>(
      l1selT, T256, 256, wb_mlp_w1, 0, 256, h1raw, T256, 256, mlp_b1, nullptr, 0, 256, 1.0f);
  row_ln_kernel<256><<<2048, 256, 0, stream>>>(h1raw, h1T, mlp_g1, mlp_be1, 0.0f);
  // G2: x2T[n][o] = h1T · mlp_w2^T + b2        (M=1024,N=512,K=256) -> bf16
  gemm_bf16<true, false, false, true><<<dim3(4, 8, 8), 256, 0, stream>>>(
      h1T, T256, 256, wb_mlp_w2, 0, 256, x2T, T512, 512, mlp_b2, nullptr, 0, 256, 1.0f);

  // --- q/k/v inputs ---
  transpose_posq_kernel<<<dim3(16, 8, 8), dim3(64, 4), 0, stream>>>(
      l2, xyz2, posw, qinT, l2T);
  kin_kernel<<<8192, 128, 0, stream>>>(x2T, p1selT, posw, kinT);

  // G4: qT = qinT · qw^T    (M=1024,N=512,K=512) -> bf16
  gemm_bf16<false, false, false, true><<<dim3(4, 8, 8), 256, 0, stream>>>(
      qinT, T512, 512, wb_qw, 0, 512, qT, T512, 512, nullptr, nullptr, 0, 512, 1.0f);
  // G5: kT = kinT · kw^T
  gemm_bf16<false, false, false, true><<<dim3(4, 8, 8), 256, 0, stream>>>(
      kinT, T512, 512, wb_kw, 0, 512, kT, T512, 512, nullptr, nullptr, 0, 512, 1.0f);
  // G6: v[c][m] = vw · x2T^T (M=512,N=1024,K=512) -> bf16 channel-major
  gemm_bf16<false, false, false, true><<<dim3(8, 4, 8), 256, 0, stream>>>(
      wb_vw, 0, 512, x2T, T512, 512, vbf, T512, 1024, nullptr, nullptr, 0, 512, 1.0f);

  // --- attention ---
  // G7: e[n][m] = (qT · kT^T) / scale  (M=1024,N=1024,K=512) -> f32
  gemm_bf16<false, false, false, false><<<dim3(8, 8, 8), 256, 0, stream>>>(
      qT, T512, 512, kT, T512, 512, e, T1024, 1024, nullptr, nullptr, 0, 512, inv_scale);
  softmax_bf16_kernel<<<8192, 256, 0, stream>>>(e, att);
  // G8: oraw[n][c] = att · v^T + l2T   (M=1024,N=512,K=1024) -> f32
  gemm_bf16<false, false, true, false><<<dim3(4, 8, 8), 256, 0, stream>>>(
      att, T1024, 1024, vbf, T512, 1024, oraw, T512, 512, nullptr, l2T, T512, 1024, 1.0f);

  // --- head ---
  row_ln_kernel<512><<<2048, 256, 0, stream>>>(oraw, o1T, norm_g, norm_b, 0.01f);
  // G9: g1raw = o1T · m1_w1^T + b1    (M=1024,N=512,K=512) -> f32
  gemm_bf16<true, false, false, false><<<dim3(4, 8, 8), 256, 0, stream>>>(
      o1T, T512, 512, wb_m1w1, 0, 512, g1raw, T512, 512, m1_b1, nullptr, 0, 512, 1.0f);
  row_ln_kernel<512><<<2048, 256, 0, stream>>>(g1raw, g2T, m1_g, m1_be, 0.0f);
  // G10: out[r][n] = m1_w2 · g2T^T + b2  (M=256,N=1024,K=512) -> f32 to d_out
  gemm_bf16<false, true, false, false><<<dim3(8, 2, 8), 256, 0, stream>>>(
      wb_m1w2, 0, 512, g2T, T512, 512, outp, 256L * 1024, 1024, m1_b2, nullptr, 0, 512, 1.0f);
}

// Round 3
// 355.437 us; speedup vs baseline: 3.1137x; 1.2947x over previous
//
#include <hip/hip_runtime.h>
#include <math.h>

// ---------------------------------------------------------------------------
// (B, Cin, Cout, Rout, N1, N2) = (8, 256, 512, 256, 4096, 1024)
// Activations token-major X[b][n][c] (c contiguous) except v [c][m].
// ---------------------------------------------------------------------------

typedef __attribute__((ext_vector_type(8))) short short8x;
typedef __attribute__((ext_vector_type(4))) float f32x4;

__device__ __forceinline__ unsigned short f2b(float f) {
  unsigned int u = __float_as_uint(f);
  unsigned int r = u + 0x7FFFu + ((u >> 16) & 1u);
  return (unsigned short)(r >> 16);
}
__device__ __forceinline__ float b2f(unsigned short h) {
  return __uint_as_float(((unsigned int)h) << 16);
}

__device__ __forceinline__ void cp16(const unsigned short* g, unsigned short* l) {
  __builtin_amdgcn_global_load_lds(
      (const __attribute__((address_space(1))) void*)g,
      (__attribute__((address_space(3))) void*)l, 16, 0, 0);
}

// ===========================================================================
// Selection path (exact f32 — top-k set identity requires it)
// ===========================================================================
__global__ void __launch_bounds__(256) sel_qw_kernel(
    const float* __restrict__ l1, const float* __restrict__ q1w,
    const float* __restrict__ k1w, float* __restrict__ wvec) {
  const int b = blockIdx.x;
  const int t = threadIdx.x;
  __shared__ float col[256];
  __shared__ float q1v[512];
  col[t] = l1[(long)b * 256 * 4096 + (long)t * 4096];
  __syncthreads();
  for (int o = t; o < 512; o += 256) {
    float s = 0.f;
    const float* row = q1w + (long)o * 256;
    for (int c = 0; c < 256; ++c) s += row[c] * col[c];
    q1v[o] = s;
  }
  __syncthreads();
  float s = 0.f;
  for (int o = 0; o < 512; ++o) s += k1w[(long)o * 256 + t] * q1v[o];
  wvec[b * 256 + t] = s;
}

__global__ void __launch_bounds__(256) sel_scores_kernel(
    const float* __restrict__ l1, const float* __restrict__ wvec,
    float* __restrict__ scores) {
  const int b = blockIdx.y;
  const int m = blockIdx.x * 256 + threadIdx.x;
  __shared__ float w[256];
  w[threadIdx.x] = wvec[b * 256 + threadIdx.x];
  __syncthreads();
  const float* base = l1 + (long)b * 256 * 4096 + m;
  float s = 0.f;
  for (int c = 0; c < 256; ++c) s += w[c] * base[(long)c * 4096];
  scores[b * 4096 + m] = s;
}

// ===========================================================================
// Exact top-1024 SET per batch (radix select), output INDEX-SORTED ascending.
// (Downstream is permutation-invariant in the selected order; ascending order
//  gives the gather kernel cache-line locality.)
// ===========================================================================
__global__ void __launch_bounds__(256) topk_select_kernel(
    const float* __restrict__ scores, int* __restrict__ idx_out) {
  const int b = blockIdx.x;
  const int t = threadIdx.x;
  __shared__ unsigned int keys[4096];
  __shared__ unsigned int hist[256];
  __shared__ unsigned int sc_prefix, sc_krem;
  __shared__ int s_bin;
  __shared__ unsigned int partial_gt[256], partial_eq[256];

  for (int m = t; m < 4096; m += 256) {
    unsigned int u = __float_as_uint(scores[b * 4096 + m]);
    u ^= (u & 0x80000000u) ? 0xFFFFFFFFu : 0x80000000u;
    keys[m] = u;
  }
  if (t == 0) { sc_prefix = 0u; sc_krem = 1024u; }
  __syncthreads();

  unsigned int prefmask = 0u;
  for (int shift = 24; shift >= 0; shift -= 8) {
    hist[t] = 0u;
    if (t == 0) s_bin = 0;
    __syncthreads();
    const unsigned int prefix = sc_prefix;
    for (int m = t; m < 4096; m += 256) {
      unsigned int key = keys[m];
      if ((key & prefmask) == prefix) atomicAdd(&hist[(key >> shift) & 255u], 1u);
    }
    __syncthreads();
    // inclusive suffix-sum of hist (Hillis-Steele)
    for (int off = 1; off < 256; off <<= 1) {
      unsigned int v = hist[t] + ((t + off < 256) ? hist[t + off] : 0u);
      __syncthreads();
      hist[t] = v;
      __syncthreads();
    }
    const unsigned int krem = sc_krem;
    if (hist[t] >= krem) atomicMax(&s_bin, t);  // suffix non-increasing
    __syncthreads();
    if (t == 0) {
      const int bin = s_bin;
      sc_krem = krem - ((bin < 255) ? hist[bin + 1] : 0u);
      sc_prefix = prefix | ((unsigned int)bin << shift);
    }
    prefmask |= (0xFFu << shift);
    __syncthreads();
  }
  const unsigned int cutoff = sc_prefix;
  const unsigned int need = sc_krem;

  // per-chunk counts (16 contiguous elements per thread = index order)
  unsigned int gt = 0u, eq = 0u;
  const int base = t * 16;
  for (int i = 0; i < 16; ++i) {
    unsigned int key = keys[base + i];
    gt += (key > cutoff);
    eq += (key == cutoff);
  }
  partial_gt[t] = gt;
  partial_eq[t] = eq;
  __syncthreads();
  // inclusive prefix scans
  for (int off = 1; off < 256; off <<= 1) {
    unsigned int g = partial_gt[t] + ((t >= off) ? partial_gt[t - off] : 0u);
    unsigned int e2 = partial_eq[t] + ((t >= off) ? partial_eq[t - off] : 0u);
    __syncthreads();
    partial_gt[t] = g;
    partial_eq[t] = e2;
    __syncthreads();
  }
  const unsigned int pref_gt = partial_gt[t] - gt;   // exclusive
  const unsigned int pref_eq = partial_eq[t] - eq;
  // index-sorted compaction: selected = gt OR (eq AND global_eq_rank < need)
  unsigned int pos = pref_gt + ((pref_eq < need) ? pref_eq : need);
  unsigned int eqr = pref_eq;
  for (int i = 0; i < 16; ++i) {
    unsigned int key = keys[base + i];
    bool sel = (key > cutoff);
    if (key == cutoff) sel = sel || (eqr++ < need);
    if (sel) idx_out[b * 1024 + (pos++)] = base + i;
  }
}

// ===========================================================================
// Gather (idx ascending): l1selT[b][j][c] bf16 token-major, p1selT[b][j][d].
// 64 tokens x 128 channels per block -> 256 blocks, 4-deep load ILP.
// ===========================================================================
__global__ void __launch_bounds__(256) gather_sel_kernel(
    const float* __restrict__ l1, const float* __restrict__ xyz1,
    const int* __restrict__ idx, unsigned short* __restrict__ l1selT,
    float* __restrict__ p1selT) {
  const int b = blockIdx.z;
  const int j = blockIdx.x * 64 + (threadIdx.x & 63);
  const int cz = blockIdx.y;
  const int cg = threadIdx.x >> 6;
  const int ix = idx[b * 1024 + j];
  const float* src = l1 + (long)b * 256 * 4096 + ix;
  unsigned short* dst = l1selT + ((long)b * 1024 + j) * 256;
#pragma unroll
  for (int it = 0; it < 8; ++it) {
    const int c = cz * 128 + it * 16 + cg * 4;
    const float x0 = src[(long)(c + 0) * 4096];
    const float x1 = src[(long)(c + 1) * 4096];
    const float x2 = src[(long)(c + 2) * 4096];
    const float x3 = src[(long)(c + 3) * 4096];
    ushort4 o;
    o.x = f2b(x0); o.y = f2b(x1); o.z = f2b(x2); o.w = f2b(x3);
    *(ushort4*)&dst[c] = o;
  }
  if (cz == 0 && cg == 0) {
    float* dp = p1selT + ((long)b * 1024 + j) * 3;
#pragma unroll
    for (int d = 0; d < 3; ++d) dp[d] = xyz1[((long)b * 3 + d) * 4096 + ix];
  }
}

// ===========================================================================
// Weight convert f32 -> bf16
// ===========================================================================
__global__ void __launch_bounds__(256) conv_weights_kernel(
    const float* w0, const float* w1, const float* w2, const float* w3,
    const float* w4, const float* w5, const float* w6,
    unsigned short* d0, unsigned short* d1, unsigned short* d2,
    unsigned short* d3, unsigned short* d4, unsigned short* d5,
    unsigned short* d6) {
  const float* src;
  unsigned short* dst;
  int n;
  switch (blockIdx.y) {
    case 0: src = w0; dst = d0; n = 65536; break;
    case 1: src = w1; dst = d1; n = 131072; break;
    case 2: src = w2; dst = d2; n = 262144; break;
    case 3: src = w3; dst = d3; n = 262144; break;
    case 4: src = w4; dst = d4; n = 262144; break;
    case 5: src = w5; dst = d5; n = 262144; break;
    default: src = w6; dst = d6; n = 131072; break;
  }
  const int i = (blockIdx.x * 256 + threadIdx.x) * 4;
  if (i < n) {
    const float4 v = *(const float4*)(src + i);
    ushort4 o;
    o.x = f2b(v.x); o.y = f2b(v.y); o.z = f2b(v.z); o.w = f2b(v.w);
    *(ushort4*)(dst + i) = o;
  }
}

// ===========================================================================
// Transpose l2 -> token-major + pos_q; also l2T f32 residual copy.
// ===========================================================================
__global__ void __launch_bounds__(256) transpose_posq_kernel(
    const float* __restrict__ l2, const float* __restrict__ xyz2,
    const float* __restrict__ posw, unsigned short* __restrict__ qinT,
    float* __restrict__ l2T) {
  const int b = blockIdx.z;
  const int n0 = blockIdx.x * 64, c0 = blockIdx.y * 64;
  const int tx = threadIdx.x, ty = threadIdx.y;
  __shared__ float tile[64][65];
  __shared__ float sx[3][64];
  const float* l2b = l2 + (long)b * 512 * 1024;
  for (int r = 0; r < 16; ++r) {
    const int c = ty * 16 + r;
    tile[c][tx] = l2b[(long)(c0 + c) * 1024 + n0 + tx];
  }
  if (ty < 3) sx[ty][tx] = xyz2[((long)b * 3 + ty) * 1024 + n0 + tx];
  __syncthreads();
  const int c = c0 + tx;
  const float p0 = posw[c * 3], p1 = posw[c * 3 + 1], p2 = posw[c * 3 + 2];
  for (int r = 0; r < 16; ++r) {
    const int nl = ty * 16 + r;
    const float val = tile[tx][nl];
    const long o = ((long)b * 1024 + n0 + nl) * 512 + c;
    l2T[o] = val;
    qinT[o] = f2b(val + p0 * sx[0][nl] + p1 * sx[1][nl] + p2 * sx[2][nl]);
  }
}

// ===========================================================================
// kinT[n][c] bf16 = x2T[n][c] + posw[c]·p1selT[n][:]
// ===========================================================================
__global__ void __launch_bounds__(128) kin_kernel(
    const unsigned short* __restrict__ x2T, const float* __restrict__ p1selT,
    const float* __restrict__ posw, unsigned short* __restrict__ kinT) {
  const long row = blockIdx.x;
  const int t = threadIdx.x;
  const float q0 = p1selT[row * 3], q1 = p1selT[row * 3 + 1], q2 = p1selT[row * 3 + 2];
  const int c = t * 4;
  const ushort4 xv = *(const ushort4*)&x2T[row * 512 + c];
  ushort4 o;
  o.x = f2b(b2f(xv.x) + posw[(c + 0) * 3] * q0 + posw[(c + 0) * 3 + 1] * q1 + posw[(c + 0) * 3 + 2] * q2);
  o.y = f2b(b2f(xv.y) + posw[(c + 1) * 3] * q0 + posw[(c + 1) * 3 + 1] * q1 + posw[(c + 1) * 3 + 2] * q2);
  o.z = f2b(b2f(xv.z) + posw[(c + 2) * 3] * q0 + posw[(c + 2) * 3 + 1] * q1 + posw[(c + 2) * 3 + 2] * q2);
  o.w = f2b(b2f(xv.w) + posw[(c + 3) * 3] * q0 + posw[(c + 3) * 3 + 1] * q1 + posw[(c + 3) * 3 + 2] * q2);
  *(ushort4*)&kinT[row * 512 + c] = o;
}

// ===========================================================================
// MFMA bf16 GEMM, double-buffered LDS k-loop (1 barrier/iter).
// D[M][N] = alpha*A[M][K]·Bt[N][K]^T (+bias)(+res). 128x128 tile, 4 waves.
// Bt += (b&7)*sB + (b>>3)*sB8 lets one dispatch cover two weight matrices.
// ===========================================================================
template <bool BIAS_COL, bool BIAS_ROW, bool RES, bool OUT_BF16>
__global__ void __launch_bounds__(256) gemm_bf16(
    const unsigned short* __restrict__ A, long sA, int ldA,
    const unsigned short* __restrict__ Bt, long sB, int ldB, long sB8,
    void* __restrict__ Yv, long sY, int ldY,
    const float* __restrict__ bias, const float* __restrict__ res, long sR,
    int K, float alpha) {
  __shared__ __align__(16) unsigned short ldsA[2][128 * 32];
  __shared__ __align__(16) unsigned short ldsB[2][128 * 32];
  const int tid = threadIdx.x;
  const int lane = tid & 63;
  const int wv = tid >> 6;
  const int wm = wv >> 1, wn = wv & 1;
  const int n0 = blockIdx.x * 128, m0 = blockIdx.y * 128, b = blockIdx.z;
  A += (long)b * sA;
  Bt += (long)(b & 7) * sB + (long)(b >> 3) * sB8;
  const int lane15 = lane & 15, q = lane >> 4;

  const int srow0 = wv * 32 + (lane >> 2);
  const int srow1 = srow0 + 16;
  const int ks0 = ((lane & 3) ^ ((srow0 >> 1) & 3)) << 3;
  const int ks1 = ((lane & 3) ^ ((srow1 >> 1) & 3)) << 3;
  const unsigned short* gA0 = A + (long)(m0 + srow0) * ldA + ks0;
  const unsigned short* gA1 = A + (long)(m0 + srow1) * ldA + ks1;
  const unsigned short* gB0 = Bt + (long)(n0 + srow0) * ldB + ks0;
  const unsigned short* gB1 = Bt + (long)(n0 + srow1) * ldB + ks1;
  unsigned short* lA0[2] = {&ldsA[0][(wv * 32) * 32], &ldsA[1][(wv * 32) * 32]};
  unsigned short* lA1[2] = {&ldsA[0][(wv * 32 + 16) * 32], &ldsA[1][(wv * 32 + 16) * 32]};
  unsigned short* lB0[2] = {&ldsB[0][(wv * 32) * 32], &ldsB[1][(wv * 32) * 32]};
  unsigned short* lB1[2] = {&ldsB[0][(wv * 32 + 16) * 32], &ldsB[1][(wv * 32 + 16) * 32]};

  // prologue: stage k0=0 into buffer 0
  cp16(gA0, lA0[0]); cp16(gA1, lA1[0]);
  cp16(gB0, lB0[0]); cp16(gB1, lB1[0]);

  f32x4 acc[4][4] = {};
  int cur = 0;
  for (int k0 = 0; k0 < K; k0 += 32) {
    __syncthreads();  // drains vmcnt: buffer `cur` is ready; prev reads done
    if (k0 + 32 < K) {
      const int nk = k0 + 32;
      cp16(gA0 + nk, lA0[cur ^ 1]); cp16(gA1 + nk, lA1[cur ^ 1]);
      cp16(gB0 + nk, lB0[cur ^ 1]); cp16(gB1 + nk, lB1[cur ^ 1]);
    }
    short8x af[4], bfr[4];
#pragma unroll
    for (int i = 0; i < 4; ++i) {
      const int m = wm * 64 + i * 16 + lane15;
      af[i] = *(const short8x*)&ldsA[cur][m * 32 + ((q ^ ((m >> 1) & 3)) << 3)];
      const int n = wn * 64 + i * 16 + lane15;
      bfr[i] = *(const short8x*)&ldsB[cur][n * 32 + ((q ^ ((n >> 1) & 3)) << 3)];
    }
#pragma unroll
    for (int i = 0; i < 4; ++i)
#pragma unroll
      for (int j = 0; j < 4; ++j)
        acc[i][j] = __builtin_amdgcn_mfma_f32_16x16x32_bf16(af[i], bfr[j], acc[i][j], 0, 0, 0);
    cur ^= 1;
  }

  // epilogue: C/D layout col=lane&15, row=(lane>>4)*4+reg
  float* Yf = (float*)Yv + (OUT_BF16 ? 0 : (long)b * sY);
  unsigned short* Yh = (unsigned short*)Yv + (OUT_BF16 ? (long)b * sY : 0);
  if (RES) res += (long)b * sR;
#pragma unroll
  for (int i = 0; i < 4; ++i) {
#pragma unroll
    for (int j = 0; j < 4; ++j) {
      const int n_g = n0 + wn * 64 + j * 16 + lane15;
      const float bc = BIAS_COL ? bias[n_g] : 0.f;
#pragma unroll
      for (int r = 0; r < 4; ++r) {
        const int m_g = m0 + wm * 64 + i * 16 + q * 4 + r;
        float y = acc[i][j][r] * alpha + bc;
        if (BIAS_ROW) y += bias[m_g];
        const long off = (long)m_g * ldY + n_g;
        if (RES) y += res[off];
        if (OUT_BF16) Yh[off] = f2b(y);
        else Yf[off] = y;
      }
    }
  }
}

// ===========================================================================
// Row LayerNorm (+act), f32 in -> bf16 out. One wave per row.
// ===========================================================================
template <int C>
__global__ void __launch_bounds__(256) row_ln_kernel(
    const float* __restrict__ X, unsigned short* __restrict__ Y,
    const float* __restrict__ g, const float* __restrict__ be, float slope) {
  const int lane = threadIdx.x & 63;
  const long row = (long)blockIdx.x * 4 + (threadIdx.x >> 6);
  const float* xr = X + row * C;
  constexpr int V = C / 256;
  float4 v[V];
  float s = 0.f, sq = 0.f;
#pragma unroll
  for (int u = 0; u < V; ++u) {
    v[u] = ((const float4*)xr)[lane * V + u];
    s += v[u].x + v[u].y + v[u].z + v[u].w;
    sq += v[u].x * v[u].x + v[u].y * v[u].y + v[u].z * v[u].z + v[u].w * v[u].w;
  }
#pragma unroll
  for (int off = 32; off > 0; off >>= 1) {
    s += __shfl_xor(s, off);
    sq += __shfl_xor(sq, off);
  }
  const float mean = s / (float)C;
  const float var = sq / (float)C - mean * mean;
  const float rstd = rsqrtf(var + 1e-5f);
  unsigned short* yr = Y + row * C;
#pragma unroll
  for (int u = 0; u < V; ++u) {
    const int c = (lane * V + u) * 4;
    const float4 gv = ((const float4*)g)[lane * V + u];
    const float4 bv = ((const float4*)be)[lane * V + u];
    float y0 = (v[u].x - mean) * rstd * gv.x + bv.x;
    float y1 = (v[u].y - mean) * rstd * gv.y + bv.y;
    float y2 = (v[u].z - mean) * rstd * gv.z + bv.z;
    float y3 = (v[u].w - mean) * rstd * gv.w + bv.w;
    y0 = y0 > 0.f ? y0 : slope * y0;
    y1 = y1 > 0.f ? y1 : slope * y1;
    y2 = y2 > 0.f ? y2 : slope * y2;
    y3 = y3 > 0.f ? y3 : slope * y3;
    ushort4 o;
    o.x = f2b(y0); o.y = f2b(y1); o.z = f2b(y2); o.w = f2b(y3);
    *(ushort4*)&yr[c] = o;
  }
}

// ===========================================================================
// Softmax over rows of 1024, f32 in -> bf16 out
// ===========================================================================
__global__ void __launch_bounds__(256) softmax_bf16_kernel(
    const float* __restrict__ E, unsigned short* __restrict__ att) {
  const long row = blockIdx.x;
  const int t = threadIdx.x;
  float4 v = ((const float4*)(E + row * 1024))[t];
  float m = fmaxf(fmaxf(v.x, v.y), fmaxf(v.z, v.w));
  __shared__ float sm[256];
  sm[t] = m;
  __syncthreads();
  for (int s = 128; s > 0; s >>= 1) {
    if (t < s) sm[t] = fmaxf(sm[t], sm[t + s]);
    __syncthreads();
  }
  m = sm[0];
  __syncthreads();
  v.x = expf(v.x - m); v.y = expf(v.y - m);
  v.z = expf(v.z - m); v.w = expf(v.w - m);
  sm[t] = v.x + v.y + v.z + v.w;
  __syncthreads();
  for (int s = 128; s > 0; s >>= 1) {
    if (t < s) sm[t] += sm[t + s];
    __syncthreads();
  }
  const float inv = 1.f / sm[0];
  ushort4 o;
  o.x = f2b(v.x * inv); o.y = f2b(v.y * inv);
  o.z = f2b(v.z * inv); o.w = f2b(v.w * inv);
  ((ushort4*)(att + row * 1024))[t] = o;
}

// ===========================================================================
// Launch
// ===========================================================================
extern "C" void kernel_launch(void* const* d_in, const int* in_sizes, int n_in,
                              void* d_out, int out_size, void* d_ws,
                              size_t ws_size, hipStream_t stream) {
  const float* l1 = (const float*)d_in[0];
  const float* xyz1 = (const float*)d_in[1];
  const float* l2 = (const float*)d_in[2];
  const float* xyz2 = (const float*)d_in[3];
  const float* q1w = (const float*)d_in[4];
  const float* k1w = (const float*)d_in[5];
  const float* mlp_w1 = (const float*)d_in[6];
  const float* mlp_b1 = (const float*)d_in[7];
  const float* mlp_g1 = (const float*)d_in[8];
  const float* mlp_be1 = (const float*)d_in[9];
  const float* mlp_w2 = (const float*)d_in[10];
  const float* mlp_b2 = (const float*)d_in[11];
  const float* qw = (const float*)d_in[12];
  const float* kw = (const float*)d_in[13];
  const float* vw = (const float*)d_in[14];
  const float* posw = (const float*)d_in[15];
  const float* norm_g = (const float*)d_in[16];
  const float* norm_b = (const float*)d_in[17];
  const float* m1_w1 = (const float*)d_in[18];
  const float* m1_b1 = (const float*)d_in[19];
  const float* m1_g = (const float*)d_in[20];
  const float* m1_be = (const float*)d_in[21];
  const float* m1_w2 = (const float*)d_in[22];
  const float* m1_b2 = (const float*)d_in[23];

  char* ws = (char*)d_ws;
  const long MiB = 1048576;
  unsigned short* wb_mlp_w1 = (unsigned short*)(ws + 0);
  unsigned short* wb_mlp_w2 = (unsigned short*)(ws + 131072);
  unsigned short* wb_qw = (unsigned short*)(ws + 393216);
  unsigned short* wb_kw = (unsigned short*)(ws + 917504);
  unsigned short* wb_vw = (unsigned short*)(ws + 1441792);
  unsigned short* wb_m1w1 = (unsigned short*)(ws + 1966080);
  unsigned short* wb_m1w2 = (unsigned short*)(ws + 2490368);
  float* scores = (float*)(ws + 2752512);
  float* wvec = (float*)(ws + 2883584);
  int* idxb = (int*)(ws + 2891776);
  float* p1selT = (float*)(ws + 2924544);
  float* e = (float*)(ws + 4 * MiB);                        // [4,36) f32
  unsigned short* l1selT = (unsigned short*)(ws + 4 * MiB); // dead before e
  float* h1raw = (float*)(ws + 8 * MiB);                    // dead before e
  unsigned short* h1T = (unsigned short*)(ws + 16 * MiB);   // dead before e
  unsigned short* qinT = (unsigned short*)(ws + 20 * MiB);  // dead before e
  unsigned short* kinT = (unsigned short*)(ws + 28 * MiB);  // contiguous w/ qinT
  float* l2T = (float*)(ws + 36 * MiB);                     // [36,52)
  unsigned short* x2T = (unsigned short*)(ws + 52 * MiB);   // [52,60)
  unsigned short* g2T = (unsigned short*)(ws + 52 * MiB);   // reuse after x2T dead
  unsigned short* qT = (unsigned short*)(ws + 60 * MiB);    // [60,68)
  unsigned short* kT = (unsigned short*)(ws + 68 * MiB);    // [68,76) contiguous w/ qT
  float* oraw = (float*)(ws + 60 * MiB);                    // reuse qT/kT
  unsigned short* vbf = (unsigned short*)(ws + 76 * MiB);   // [76,84)
  unsigned short* att = (unsigned short*)(ws + 84 * MiB);   // [84,100)
  float* g1raw = (float*)(ws + 84 * MiB);                   // reuse after att dead
  unsigned short* o1T = (unsigned short*)(ws + 100 * MiB);  // [100,108)
  float* outp = (float*)d_out;

  const float inv_scale = 1.0f / sqrtf(512.0f);
  const long T256 = 1024L * 256, T512 = 1024L * 512, T1024 = 1024L * 1024;

  conv_weights_kernel<<<dim3(256, 7), 256, 0, stream>>>(
      mlp_w1, mlp_w2, qw, kw, vw, m1_w1, m1_w2,
      wb_mlp_w1, wb_mlp_w2, wb_qw, wb_kw, wb_vw, wb_m1w1, wb_m1w2);
  sel_qw_kernel<<<8, 256, 0, stream>>>(l1, q1w, k1w, wvec);
  sel_scores_kernel<<<dim3(16, 8), 256, 0, stream>>>(l1, wvec, scores);
  topk_select_kernel<<<8, 256, 0, stream>>>(scores, idxb);
  gather_sel_kernel<<<dim3(16, 2, 8), 256, 0, stream>>>(l1, xyz1, idxb, l1selT, p1selT);

  // --- point MLP ---
  gemm_bf16<true, false, false, false><<<dim3(2, 8, 8), 256, 0, stream>>>(
      l1selT, T256, 256, wb_mlp_w1, 0, 256, 0, h1raw, T256, 256, mlp_b1, nullptr, 0, 256, 1.0f);
  row_ln_kernel<256><<<2048, 256, 0, stream>>>(h1raw, h1T, mlp_g1, mlp_be1, 0.0f);
  gemm_bf16<true, false, false, true><<<dim3(4, 8, 8), 256, 0, stream>>>(
      h1T, T256, 256, wb_mlp_w2, 0, 256, 0, x2T, T512, 512, mlp_b2, nullptr, 0, 256, 1.0f);

  // --- q/k/v inputs ---
  transpose_posq_kernel<<<dim3(16, 8, 8), dim3(64, 4), 0, stream>>>(
      l2, xyz2, posw, qinT, l2T);
  kin_kernel<<<8192, 128, 0, stream>>>(x2T, p1selT, posw, kinT);

  // --- merged q & k projections (z=0..7 -> q, 8..15 -> k) ---
  gemm_bf16<false, false, false, true><<<dim3(4, 8, 16), 256, 0, stream>>>(
      qinT, T512, 512, wb_qw, 0, 512, 262144, qT, T512, 512, nullptr, nullptr, 0, 512, 1.0f);
  // --- v: v[c][m] = vw · x2T^T ---
  gemm_bf16<false, false, false, true><<<dim3(8, 4, 8), 256, 0, stream>>>(
      wb_vw, 0, 512, x2T, T512, 512, 0, vbf, T512, 1024, nullptr, nullptr, 0, 512, 1.0f);

  // --- attention ---
  gemm_bf16<false, false, false, false><<<dim3(8, 8, 8), 256, 0, stream>>>(
      qT, T512, 512, kT, T512, 512, 0, e, T1024, 1024, nullptr, nullptr, 0, 512, inv_scale);
  softmax_bf16_kernel<<<8192, 256, 0, stream>>>(e, att);
  gemm_bf16<false, false, true, false><<<dim3(4, 8, 8), 256, 0, stream>>>(
      att, T1024, 1024, vbf, T512, 1024, 0, oraw, T512, 512, nullptr, l2T, T512, 1024, 1.0f);

  // --- head ---
  row_ln_kernel<512><<<2048, 256, 0, stream>>>(oraw, o1T, norm_g, norm_b, 0.01f);
  gemm_bf16<true, false, false, false><<<dim3(4, 8, 8), 256, 0, stream>>>(
      o1T, T512, 512, wb_m1w1, 0, 512, 0, g1raw, T512, 512, m1_b1, nullptr, 0, 512, 1.0f);
  row_ln_kernel<512><<<2048, 256, 0, stream>>>(g1raw, g2T, m1_g, m1_be, 0.0f);
  gemm_bf16<false, true, false, false><<<dim3(8, 2, 8), 256, 0, stream>>>(
      wb_m1w2, 0, 512, g2T, T512, 512, 0, outp, 256L * 1024, 1024, m1_b2, nullptr, 0, 512, 1.0f);
}